// Round 5
// baseline (925.200 us; speedup 1.0000x reference)
//
#include <hip/hip_runtime.h>

// GCN 2-layer + pool + head via col-binned edges (64-node buckets -> LDS accumulation).
// R5: k_layer was latency/issue-bound (R4: 56 cyc/edge/CU, VALUBusy 4.6%, FETCH already
// minimal). Fix: no LDS edge staging / no chunk barriers; 8-lane groups with dword gathers
// (8 edges per gather instr); U=8 unroll -> 16 VMEM in flight per wave; dinv[row] folded
// into the bf16 gather table (gx = dinv*(x@W)) so k_prenormE is deleted.

#define SH 6                 // log2 nodes per bucket
#define RB 64                // nodes per bucket
#define KMAX 2048            // max buckets (N <= 131072: row packs in 17 bits)
#define TPB 256

typedef unsigned short ushort_t;

__device__ __forceinline__ ushort_t f2bf(float x) {
    unsigned u = __float_as_uint(x);
    u += 0x7FFFu + ((u >> 16) & 1u);   // RNE
    return (ushort_t)(u >> 16);
}
__device__ __forceinline__ float bf2f(ushort_t u) {
    return __uint_as_float(((unsigned)u) << 16);
}

// ---------- binning ----------

__global__ void k_count(const int* __restrict__ col, unsigned* __restrict__ bucketCount,
                        int E, int K) {
    __shared__ unsigned lh[KMAX];
    for (int i = threadIdx.x; i < K; i += blockDim.x) lh[i] = 0u;
    __syncthreads();
    for (long long e = (long long)blockIdx.x * blockDim.x + threadIdx.x; e < E;
         e += (long long)gridDim.x * blockDim.x)
        atomicAdd(&lh[col[e] >> SH], 1u);
    __syncthreads();
    for (int i = threadIdx.x; i < K; i += blockDim.x)
        if (lh[i]) atomicAdd(&bucketCount[i], lh[i]);
}

__global__ void k_scan(const unsigned* __restrict__ cnt, unsigned* __restrict__ start,
                       unsigned* __restrict__ cursor, int K) {
    __shared__ unsigned a[KMAX], b[KMAX];
    int t = threadIdx.x;  // 1024
    for (int i = t; i < KMAX; i += 1024) a[i] = (i < K) ? cnt[i] : 0u;
    __syncthreads();
    unsigned *src = a, *dst = b;
    for (int off = 1; off < KMAX; off <<= 1) {
        for (int i = t; i < KMAX; i += 1024)
            dst[i] = (i >= off) ? src[i] + src[i - off] : src[i];
        __syncthreads();
        unsigned* tmp = src; src = dst; dst = tmp;
    }
    for (int i = t; i < K; i += 1024) {
        unsigned ex = (i == 0) ? 0u : src[i - 1];
        start[i] = ex; cursor[i] = ex;
    }
}

__global__ void k_binscatter(const int* __restrict__ row, const int* __restrict__ col,
                             const float* __restrict__ w, unsigned* __restrict__ cursor,
                             uint2* __restrict__ brcw, int E, int K) {
    __shared__ unsigned lh[KMAX], lb[KMAX];
    int T = blockDim.x;
    int tile = (E + gridDim.x - 1) / gridDim.x;
    int e0 = blockIdx.x * tile, e1 = min(e0 + tile, E);
    for (int i = threadIdx.x; i < K; i += T) lh[i] = 0u;
    __syncthreads();
    for (int e = e0 + threadIdx.x; e < e1; e += T) atomicAdd(&lh[col[e] >> SH], 1u);
    __syncthreads();
    for (int i = threadIdx.x; i < K; i += T) {
        unsigned c = lh[i];
        lb[i] = c ? atomicAdd(&cursor[i], c) : 0u;
    }
    __syncthreads();
    for (int i = threadIdx.x; i < K; i += T) lh[i] = 0u;
    __syncthreads();
    for (int e = e0 + threadIdx.x; e < e1; e += T) {
        int c = col[e];
        int k = c >> SH;
        unsigned r = atomicAdd(&lh[k], 1u);
        unsigned pos = lb[k] + r;
        brcw[pos] = make_uint2((unsigned)row[e] | ((unsigned)(c & (RB - 1)) << 17),
                               __float_as_uint(w[e]));
    }
}

// ---------- per-bucket deg -> dinv; payload.y <- w * dinv[col] (bucket-local) ----------

__global__ void k_degdinv_w(uint2* __restrict__ brcw, const unsigned* __restrict__ bst,
                            const unsigned* __restrict__ bcnt, float* __restrict__ dinv, int N) {
    int k = blockIdx.x;
    int node0 = k << SH;
    __shared__ float dacc[RB];
    __shared__ float dl[RB];
    if (threadIdx.x < RB) dacc[threadIdx.x] = 1.0f;  // self-loop weight
    __syncthreads();
    unsigned s = bst[k], c = bcnt[k];
    for (unsigned j = threadIdx.x; j < c; j += blockDim.x) {
        uint2 p = brcw[s + j];
        atomicAdd(&dacc[p.x >> 17], __uint_as_float(p.y));
    }
    __syncthreads();
    if (threadIdx.x < RB) {
        float r = rsqrtf(dacc[threadIdx.x]);
        dl[threadIdx.x] = r;
        if (node0 + threadIdx.x < N) dinv[node0 + threadIdx.x] = r;
    }
    __syncthreads();
    for (unsigned j = threadIdx.x; j < c; j += blockDim.x) {
        uint2 p = brcw[s + j];
        p.y = __float_as_uint(__uint_as_float(p.y) * dl[p.x >> 17]);
        brcw[s + j] = p;
    }
}

// ---------- dense: gxb = bf16(dinv * (x @ W1)) ----------

__global__ void k_l1init(const float* __restrict__ x, const float* __restrict__ W1,
                         const float* __restrict__ dinv, ushort_t* __restrict__ gxb, int N) {
    int i = blockIdx.x * blockDim.x + threadIdx.x;
    if (i >= N) return;
    float d = dinv[i];
    float x0 = x[i * 3 + 0] * d, x1 = x[i * 3 + 1] * d, x2 = x[i * 3 + 2] * d;
    unsigned o[8];
#pragma unroll
    for (int f2 = 0; f2 < 8; f2++) {
        float a = x0 * W1[2 * f2]     + x1 * W1[16 + 2 * f2]     + x2 * W1[32 + 2 * f2];
        float b = x0 * W1[2 * f2 + 1] + x1 * W1[16 + 2 * f2 + 1] + x2 * W1[32 + 2 * f2 + 1];
        o[f2] = (unsigned)f2bf(a) | ((unsigned)f2bf(b) << 16);
    }
    uint4* dst = (uint4*)(gxb + (size_t)i * 16);
    dst[0] = make_uint4(o[0], o[1], o[2], o[3]);
    dst[1] = make_uint4(o[4], o[5], o[6], o[7]);
}

// ---------- edge scatter: 8-lane groups, dword gathers, U=8, no barriers in loop ----------

__global__ __launch_bounds__(TPB)
void k_layer(const unsigned long long* __restrict__ eb, const unsigned* __restrict__ bst,
             const unsigned* __restrict__ bcnt, const unsigned* __restrict__ gxd,
             float* __restrict__ hpart, int N) {
    int k = blockIdx.x;
    int sp = blockIdx.y, S = gridDim.y;
    int node0 = k << SH;
    __shared__ float hacc[RB * 16];  // 4KB
    int tid = threadIdx.x;
    for (int i = tid; i < RB * 16; i += TPB) hacc[i] = 0.0f;
    __syncthreads();
    unsigned s = bst[k], c = bcnt[k];
    unsigned cs = (c + S - 1) / S;
    unsigned j0 = (unsigned)sp * cs, j1 = min(j0 + cs, c);
    const unsigned long long* ebase = eb + s;
    int g = tid >> 3;   // 32 groups of 8 lanes
    int f2 = tid & 7;   // dword index within 32B row
    const unsigned GS = TPB / 8;  // 32
    unsigned j = j0 + (unsigned)g;
    // U=8: 8 meta loads + 8 dword gathers in flight before any use
    for (; j + 7 * GS < j1; j += 8 * GS) {
        unsigned long long m[8];
        unsigned d[8];
#pragma unroll
        for (int u = 0; u < 8; u++) m[u] = ebase[j + u * GS];
#pragma unroll
        for (int u = 0; u < 8; u++) d[u] = gxd[(unsigned)(m[u] & 0x1FFFFu) * 8 + f2];
#pragma unroll
        for (int u = 0; u < 8; u++) {
            float nw = __uint_as_float((unsigned)(m[u] >> 32));
            unsigned lc = (unsigned)(m[u] >> 17) & 63u;
            atomicAdd(&hacc[lc * 16 + 2 * f2],     nw * __uint_as_float(d[u] << 16));
            atomicAdd(&hacc[lc * 16 + 2 * f2 + 1], nw * __uint_as_float(d[u] & 0xFFFF0000u));
        }
    }
    for (; j < j1; j += GS) {
        unsigned long long m0 = ebase[j];
        unsigned d0 = gxd[(unsigned)(m0 & 0x1FFFFu) * 8 + f2];
        float nw = __uint_as_float((unsigned)(m0 >> 32));
        unsigned lc = (unsigned)(m0 >> 17) & 63u;
        atomicAdd(&hacc[lc * 16 + 2 * f2],     nw * __uint_as_float(d0 << 16));
        atomicAdd(&hacc[lc * 16 + 2 * f2 + 1], nw * __uint_as_float(d0 & 0xFFFF0000u));
    }
    __syncthreads();
    int nn = min(RB, N - node0);
    float* dstp = hpart + (size_t)sp * N * 16 + (size_t)node0 * 16;
    for (int i = tid; i < nn * 16; i += TPB)
        __builtin_nontemporal_store(hacc[i], dstp + i);
}

// ---------- mid: h1 = relu(b1 + dinv*gx + sum hpart); gxb <- bf16(dinv * (h1 @ W2)) ----------

__global__ void k_mid(ushort_t* __restrict__ gxb, const float* __restrict__ hpart,
                      const float* __restrict__ dinv, const float* __restrict__ b1,
                      const float* __restrict__ W2, int N, int S) {
    __shared__ float t[16][16];
    __shared__ float w2[256];
    int tid = threadIdx.x;
    int il = tid >> 4, f = tid & 15;
    int i = blockIdx.x * 16 + il;
    w2[tid] = W2[tid];
    float v = 0.0f, d = 0.0f;
    if (i < N) {
        d = dinv[i];
        v = b1[f] + d * bf2f(gxb[(size_t)i * 16 + f]);
        for (int s = 0; s < S; s++)
            v += __builtin_nontemporal_load(hpart + (size_t)s * N * 16 + (size_t)i * 16 + f);
        v = v > 0.0f ? v : 0.0f;
    }
    t[il][f] = v;
    __syncthreads();
    if (i < N) {
        float o = 0.0f;
#pragma unroll
        for (int kk = 0; kk < 16; kk++) o += t[il][kk] * w2[kk * 16 + f];
        gxb[(size_t)i * 16 + f] = f2bf(d * o);
    }
}

// ---------- pool: h2 = relu(b2 + dinv*gx2 + sum hpart) folded into batch-pool ----------

#define PC 1024
__global__ void k_pool(const ushort_t* __restrict__ gxb, const float* __restrict__ hpart,
                       const float* __restrict__ dinv, const float* __restrict__ b2,
                       const int* __restrict__ batch, float* __restrict__ pooled,
                       int N, int G, int S) {
    int b0 = blockIdx.x * PC;
    int nodes = min(PC, N - b0);
    __shared__ float lacc[64 * 16];
    __shared__ int lbat[PC];
    int tid = threadIdx.x;  // 256
    for (int i = tid; i < nodes; i += 256) lbat[i] = batch[b0 + i];
    __syncthreads();
    int gmin = lbat[0], gmax = lbat[nodes - 1];
    bool fits = (gmax - gmin < 64);
    if (fits) {
        for (int i = tid; i < 64 * 16; i += 256) lacc[i] = 0.0f;
        __syncthreads();
    }
    for (int idx = tid; idx < nodes * 16; idx += 256) {
        int i = idx >> 4, f = idx & 15;
        int n = b0 + i;
        float d = dinv[n];
        float v = b2[f] + d * bf2f(gxb[(size_t)n * 16 + f]);
        for (int s = 0; s < S; s++)
            v += __builtin_nontemporal_load(hpart + (size_t)s * N * 16 + (size_t)n * 16 + f);
        v = v > 0.0f ? v : 0.0f;
        if (fits) atomicAdd(&lacc[(lbat[i] - gmin) * 16 + f], v);
        else      atomicAdd(&pooled[lbat[i] * 16 + f], v);
    }
    if (fits) {
        __syncthreads();
        for (int idx = tid; idx < 64 * 16; idx += 256) {
            int g = gmin + (idx >> 4);
            float v = lacc[idx];
            if (g < G && v != 0.0f) atomicAdd(&pooled[g * 16 + (idx & 15)], v);
        }
    }
}

__global__ void k_final(const float* __restrict__ pooled, const float* __restrict__ Wlin,
                        const float* __restrict__ blin, float* __restrict__ out, int G) {
    int t = blockIdx.x * blockDim.x + threadIdx.x;
    int g = t / 7, j = t % 7;
    if (g >= G) return;
    float v = blin[j];
#pragma unroll
    for (int f = 0; f < 16; f++) v += pooled[g * 16 + f] * Wlin[f * 7 + j];
    out[g * 7 + j] = v;
}

static inline int cdiv_i(long long a, long long b) { return (int)((a + b - 1) / b); }

extern "C" void kernel_launch(void* const* d_in, const int* in_sizes, int n_in,
                              void* d_out, int out_size, void* d_ws, size_t ws_size,
                              hipStream_t stream) {
    const float* x     = (const float*)d_in[0];
    const int*   ei    = (const int*)d_in[1];
    const float* ew    = (const float*)d_in[2];
    const int*   batch = (const int*)d_in[3];
    const float* W1    = (const float*)d_in[4];
    const float* b1    = (const float*)d_in[5];
    const float* W2    = (const float*)d_in[6];
    const float* b2    = (const float*)d_in[7];
    const float* Wlin  = (const float*)d_in[8];
    const float* blin  = (const float*)d_in[9];
    float* out = (float*)d_out;

    const int N = in_sizes[0] / 3;
    const int E = in_sizes[2];
    const int G = out_size / 7;
    const int K = (N + RB - 1) >> SH;  // 1563 for N=100000
    const int* row = ei;
    const int* col = ei + E;

    // workspace layout (brcw first for 8B alignment)
    uint2*    brcw   = (uint2*)d_ws;                       // E * 8B
    unsigned* bcnt   = (unsigned*)(brcw + E);              // KMAX
    unsigned* bst    = bcnt + KMAX;                        // KMAX
    unsigned* bcur   = bst + KMAX;                         // KMAX
    float*    dinv   = (float*)(bcur + KMAX);              // N
    float*    pooled = dinv + N;                           // G*16
    ushort_t* gxb    = (ushort_t*)(pooled + (size_t)G * 16); // N*16 bf16 (dinv-scaled table)
    float*    hpart  = (float*)(gxb + (size_t)N * 16);     // S * N*16 fp32

    size_t fixed = (char*)hpart - (char*)d_ws;
    size_t per_part = (size_t)N * 16 * sizeof(float);
    int S = (int)((ws_size - fixed) / per_part);
    S = S < 1 ? 1 : (S > 4 ? 4 : S);

    hipMemsetAsync(bcnt, 0, KMAX * sizeof(unsigned), stream);
    hipMemsetAsync(pooled, 0, (size_t)G * 16 * sizeof(float), stream);

    // bin edges by col>>6
    k_count<<<256, TPB, 0, stream>>>(col, bcnt, E, K);
    k_scan<<<1, 1024, 0, stream>>>(bcnt, bst, bcur, K);
    k_binscatter<<<256, TPB, 0, stream>>>(row, col, ew, bcur, brcw, E, K);

    // deg -> dinv; payload.y <- w*dinv[col]
    k_degdinv_w<<<K, TPB, 0, stream>>>(brcw, bst, bcnt, dinv, N);

    // layer 1  (gx = dinv * (x@W1))
    k_l1init<<<cdiv_i(N, TPB), TPB, 0, stream>>>(x, W1, dinv, gxb, N);
    k_layer<<<dim3(K, S), TPB, 0, stream>>>((const unsigned long long*)brcw, bst, bcnt,
                                            (const unsigned*)gxb, hpart, N);
    k_mid<<<cdiv_i(N, 16), TPB, 0, stream>>>(gxb, hpart, dinv, b1, W2, N, S);

    // layer 2  (gx2 = dinv * (h1@W2))
    k_layer<<<dim3(K, S), TPB, 0, stream>>>((const unsigned long long*)brcw, bst, bcnt,
                                            (const unsigned*)gxb, hpart, N);
    k_pool<<<cdiv_i(N, PC), TPB, 0, stream>>>(gxb, hpart, dinv, b2, batch, pooled, N, G, S);

    k_final<<<cdiv_i((long long)G * 7, TPB), TPB, 0, stream>>>(pooled, Wlin, blin, out, G);
}

// Round 6
// 626.566 us; speedup vs baseline: 1.4766x; 1.4766x over previous
//
#include <hip/hip_runtime.h>

// GCN 2-layer + pool + head — flat TLP-maximal structure (R1-style), algebraically minimized.
// R3-R5 post-mortem: binned LDS-accumulation capped at ~12 G edges/s (looping waves,
// compiler-serialized dependent loads; VGPR=16-20 = no MLP), while R1's flat one-shot-wave
// kernels hit ~20 G random line-ops/s through the TCC atomic path. So: flat kernels, and
// factor dinv[col] OUT of the edge sum:
//   h[c] = b + dinv[c]*( g[c] + sum_e w_e * g[row_e] ),   g = dinv * (prev @ W)
// -> scatter pass = coalesced w + 1 random gather + 1 random atomic per edge. No norm array.

#define TPB 256

// ---------- deg: degsum[c] += w  (degsum pre-zeroed; dinv = rsqrt(1+degsum) later) ----------
__global__ void k_deg(const int* __restrict__ col, const float* __restrict__ w,
                      float* __restrict__ degsum, int E) {
    int e = blockIdx.x * blockDim.x + threadIdx.x;
    if (e < E) atomicAdd(&degsum[col[e]], w[e]);
}

// ---------- g1 = dinv * (x @ W1); also emit dinv ----------
__global__ void k_gtab(const float* __restrict__ x, const float* __restrict__ W1,
                       const float* __restrict__ degsum, float* __restrict__ dinv,
                       float* __restrict__ g, int N) {
    int i = blockIdx.x * blockDim.x + threadIdx.x;
    if (i >= N) return;
    float d = rsqrtf(1.0f + degsum[i]);   // deg >= 1 always (self-loop)
    dinv[i] = d;
    float x0 = x[i * 3 + 0] * d, x1 = x[i * 3 + 1] * d, x2 = x[i * 3 + 2] * d;
    float4* dst = (float4*)(g + (size_t)i * 16);
#pragma unroll
    for (int q = 0; q < 4; q++) {
        float4 o;
        o.x = x0 * W1[4 * q + 0] + x1 * W1[16 + 4 * q + 0] + x2 * W1[32 + 4 * q + 0];
        o.y = x0 * W1[4 * q + 1] + x1 * W1[16 + 4 * q + 1] + x2 * W1[32 + 4 * q + 1];
        o.z = x0 * W1[4 * q + 2] + x1 * W1[16 + 4 * q + 2] + x2 * W1[32 + 4 * q + 2];
        o.w = x0 * W1[4 * q + 3] + x1 * W1[16 + 4 * q + 3] + x2 * W1[32 + 4 * q + 3];
        dst[q] = o;
    }
}

// ---------- scatter: acc[col][f] += w_e * g[row][f], 16 lanes per edge, flat grid ----------
__global__ void k_scat(const int* __restrict__ row, const int* __restrict__ col,
                       const float* __restrict__ w, const float* __restrict__ g,
                       float* __restrict__ acc, int E) {
    long long t = (long long)blockIdx.x * blockDim.x + threadIdx.x;
    int e = (int)(t >> 4), f = (int)(t & 15);
    if (e >= E) return;
    int r = row[e], c = col[e];
    float v = w[e] * g[(size_t)r * 16 + f];
    atomicAdd(&acc[(size_t)c * 16 + f], v);
}

// ---------- mid: h1 = relu(b1 + dinv*(g1+acc1)); g2 = dinv * (h1 @ W2) ----------
__global__ void k_mid(const float* __restrict__ g1, const float* __restrict__ acc1,
                      const float* __restrict__ dinv, const float* __restrict__ b1,
                      const float* __restrict__ W2, float* __restrict__ g2, int N) {
    __shared__ float t[16][16];
    __shared__ float w2[256];
    int tid = threadIdx.x;
    int il = tid >> 4, f = tid & 15;
    int i = blockIdx.x * 16 + il;
    w2[tid] = W2[tid];
    float v = 0.0f, d = 0.0f;
    if (i < N) {
        d = dinv[i];
        v = b1[f] + d * (g1[(size_t)i * 16 + f] + acc1[(size_t)i * 16 + f]);
        v = v > 0.0f ? v : 0.0f;
    }
    t[il][f] = v;
    __syncthreads();
    if (i < N) {
        float o = 0.0f;
#pragma unroll
        for (int kk = 0; kk < 16; kk++) o += t[il][kk] * w2[kk * 16 + f];
        g2[(size_t)i * 16 + f] = d * o;
    }
}

// ---------- pool: h2 = relu(b2 + dinv*(g2+acc2)) folded into sorted-batch pool ----------
#define PC 1024
__global__ void k_pool(const float* __restrict__ g2, const float* __restrict__ acc2,
                       const float* __restrict__ dinv, const float* __restrict__ b2,
                       const int* __restrict__ batch, float* __restrict__ pooled,
                       int N, int G) {
    int b0 = blockIdx.x * PC;
    int nodes = min(PC, N - b0);
    __shared__ float lacc[64 * 16];
    __shared__ int lbat[PC];
    int tid = threadIdx.x;  // 256
    for (int i = tid; i < nodes; i += 256) lbat[i] = batch[b0 + i];
    __syncthreads();
    int gmin = lbat[0], gmax = lbat[nodes - 1];
    bool fits = (gmax - gmin < 64);
    if (fits) {
        for (int i = tid; i < 64 * 16; i += 256) lacc[i] = 0.0f;
        __syncthreads();
    }
    for (int idx = tid; idx < nodes * 16; idx += 256) {
        int i = idx >> 4, f = idx & 15;
        int n = b0 + i;
        float d = dinv[n];
        float v = b2[f] + d * (g2[(size_t)n * 16 + f] + acc2[(size_t)n * 16 + f]);
        v = v > 0.0f ? v : 0.0f;
        if (fits) atomicAdd(&lacc[(lbat[i] - gmin) * 16 + f], v);
        else      atomicAdd(&pooled[lbat[i] * 16 + f], v);
    }
    if (fits) {
        __syncthreads();
        for (int idx = tid; idx < 64 * 16; idx += 256) {
            int g = gmin + (idx >> 4);
            float v = lacc[idx];
            if (g < G && v != 0.0f) atomicAdd(&pooled[g * 16 + (idx & 15)], v);
        }
    }
}

__global__ void k_final(const float* __restrict__ pooled, const float* __restrict__ Wlin,
                        const float* __restrict__ blin, float* __restrict__ out, int G) {
    int t = blockIdx.x * blockDim.x + threadIdx.x;
    int g = t / 7, j = t % 7;
    if (g >= G) return;
    float v = blin[j];
#pragma unroll
    for (int f = 0; f < 16; f++) v += pooled[g * 16 + f] * Wlin[f * 7 + j];
    out[g * 7 + j] = v;
}

static inline int cdiv_i(long long a, long long b) { return (int)((a + b - 1) / b); }

extern "C" void kernel_launch(void* const* d_in, const int* in_sizes, int n_in,
                              void* d_out, int out_size, void* d_ws, size_t ws_size,
                              hipStream_t stream) {
    const float* x     = (const float*)d_in[0];
    const int*   ei    = (const int*)d_in[1];
    const float* ew    = (const float*)d_in[2];
    const int*   batch = (const int*)d_in[3];
    const float* W1    = (const float*)d_in[4];
    const float* b1    = (const float*)d_in[5];
    const float* W2    = (const float*)d_in[6];
    const float* b2    = (const float*)d_in[7];
    const float* Wlin  = (const float*)d_in[8];
    const float* blin  = (const float*)d_in[9];
    float* out = (float*)d_out;

    const int N = in_sizes[0] / 3;
    const int E = in_sizes[2];
    const int G = out_size / 7;
    const int* row = ei;       // edge_index[0]
    const int* col = ei + E;   // edge_index[1]

    float* ws = (float*)d_ws;
    float* degsum = ws;                          // N
    float* dinv   = degsum + N;                  // N
    float* g1     = dinv + N;                    // N*16
    float* g2     = g1 + (size_t)N * 16;         // N*16
    float* acc1   = g2 + (size_t)N * 16;         // N*16
    float* acc2   = acc1 + (size_t)N * 16;       // N*16
    float* pooled = acc2 + (size_t)N * 16;       // G*16

    hipMemsetAsync(degsum, 0, (size_t)N * sizeof(float), stream);
    hipMemsetAsync(acc1, 0, (size_t)N * 16 * sizeof(float), stream);
    hipMemsetAsync(acc2, 0, (size_t)N * 16 * sizeof(float), stream);
    hipMemsetAsync(pooled, 0, (size_t)G * 16 * sizeof(float), stream);

    // deg
    k_deg<<<cdiv_i(E, TPB), TPB, 0, stream>>>(col, ew, degsum, E);

    // dinv + g1 = dinv*(x@W1)
    k_gtab<<<cdiv_i(N, TPB), TPB, 0, stream>>>(x, W1, degsum, dinv, g1, N);

    // layer 1 scatter: acc1[c] += w*g1[r]
    k_scat<<<cdiv_i((long long)E * 16, TPB), TPB, 0, stream>>>(row, col, ew, g1, acc1, E);

    // mid: h1 = relu(b1 + dinv*(g1+acc1)); g2 = dinv*(h1@W2)
    k_mid<<<cdiv_i(N, 16), TPB, 0, stream>>>(g1, acc1, dinv, b1, W2, g2, N);

    // layer 2 scatter: acc2[c] += w*g2[r]
    k_scat<<<cdiv_i((long long)E * 16, TPB), TPB, 0, stream>>>(row, col, ew, g2, acc2, E);

    // pool (h2 epilogue folded) + head
    k_pool<<<cdiv_i(N, PC), TPB, 0, stream>>>(g2, acc2, dinv, b2, batch, pooled, N, G);
    k_final<<<cdiv_i((long long)G * 7, TPB), TPB, 0, stream>>>(pooled, Wlin, blin, out, G);
}